// Round 5
// baseline (186.568 us; speedup 1.0000x reference)
//
#include <hip/hip_runtime.h>
#include <math.h>

#define Bn 16
#define Cn 256
#define Ln 16384
#define Mn 64
#define LN_EPS 1e-5f
#define CHUNK 512
#define NCH (Ln / CHUNK)   // 32

typedef float v4f __attribute__((ext_vector_type(4)));

// P1: fused logits + chunk-softmax numerator + weighted pooling partials.
// grid (NCH, Bn) = 512 blocks, 256 threads (2 blocks/CU).
// Phase A: logit[l] = sum_c x[b][c][l]*wm[c] + bm (float2/thread over 512 l's),
//          m = chunk max, e[l] = exp(logit-m) -> LDS, Z = chunk sum -> mz.
// Phase B: ctxU[b][ch][c] = sum_{l in chunk} x[b][c][l]*e[l] (chunk hot in L2/L3).
__global__ void k_pass1(const float* __restrict__ x, const float* __restrict__ w_mask,
                        const float* __restrict__ b_mask,
                        float* __restrict__ ctxU,   // [Bn][NCH][Cn]
                        float* __restrict__ mz) {   // [Bn][NCH][2]
    const int ch = blockIdx.x, b = blockIdx.y;
    const int t = threadIdx.x;   // 256
    const size_t xbase = (size_t)b * Cn * Ln + (size_t)ch * CHUNK;
    __shared__ float wm[Cn];
    __shared__ float e[CHUNK];
    __shared__ float red[8];
    wm[t] = w_mask[t];
    __syncthreads();

    // ---- phase A ----
    float2 acc = make_float2(0.f, 0.f);
    const float* xp = x + xbase + 2 * t;
    #pragma unroll 8
    for (int c = 0; c < Cn; ++c) {
        float2 v = *(const float2*)(xp + (size_t)c * Ln);
        const float w = wm[c];
        acc.x += v.x * w; acc.y += v.y * w;
    }
    const float bm = b_mask[0];
    acc.x += bm; acc.y += bm;

    float lm = fmaxf(acc.x, acc.y);
    for (int off = 32; off; off >>= 1) lm = fmaxf(lm, __shfl_xor(lm, off, 64));
    if ((t & 63) == 0) red[t >> 6] = lm;
    __syncthreads();
    const float m = fmaxf(fmaxf(red[0], red[1]), fmaxf(red[2], red[3]));

    float2 ev;
    ev.x = expf(acc.x - m); ev.y = expf(acc.y - m);
    *(float2*)(e + 2 * t) = ev;
    float lz = ev.x + ev.y;
    for (int off = 32; off; off >>= 1) lz += __shfl_xor(lz, off, 64);
    if ((t & 63) == 0) red[4 + (t >> 6)] = lz;
    __syncthreads();   // e[] and red[4..7] visible
    if (t == 0) {
        mz[(b * NCH + ch) * 2 + 0] = m;
        mz[(b * NCH + ch) * 2 + 1] = red[4] + red[5] + red[6] + red[7];
    }

    // ---- phase B ---- wave wv owns channels [wv*64, wv*64+64); lanes split the 512 l's
    const int wv = t >> 6, lane = t & 63;
    const float4* e4 = (const float4*)e;
    #pragma unroll 4
    for (int k = 0; k < 64; ++k) {
        const int c = wv * 64 + k;
        const float4* xr = (const float4*)(x + xbase + (size_t)c * Ln);
        float s = 0.f;
        #pragma unroll
        for (int r = 0; r < 2; ++r) {
            float4 v = xr[r * 64 + lane];
            float4 w = e4[r * 64 + lane];
            s += v.x * w.x + v.y * w.y + v.z * w.z + v.w * w.w;
        }
        for (int off = 32; off; off >>= 1) s += __shfl_xor(s, off, 64);
        if (lane == 0) ctxU[((size_t)b * NCH + ch) * Cn + c] = s;
    }
}

// K3: flash combine of chunk partials -> ctx, then tiny MLP -> add. grid Bn, block 256.
__global__ void k_mlp(const float* __restrict__ ctxU, const float* __restrict__ mz,
                      const float* __restrict__ w1, const float* __restrict__ b1,
                      const float* __restrict__ ln_g, const float* __restrict__ ln_b,
                      const float* __restrict__ w2, const float* __restrict__ b2,
                      float* __restrict__ add) {
    const int b = blockIdx.x;
    const int t = threadIdx.x;   // 256
    __shared__ float ctx_s[Cn];
    __shared__ float h_s[Mn];

    float M = -1e30f;
    for (int j = 0; j < NCH; ++j) M = fmaxf(M, mz[(b * NCH + j) * 2 + 0]);
    float Z = 0.f, s = 0.f;
    for (int j = 0; j < NCH; ++j) {
        const float mj = mz[(b * NCH + j) * 2 + 0];
        const float zj = mz[(b * NCH + j) * 2 + 1];
        const float scj = expf(mj - M);
        Z += zj * scj;
        s += ctxU[((size_t)b * NCH + j) * Cn + t] * scj;
    }
    ctx_s[t] = s / Z;
    __syncthreads();

    // h[m] = b1[m] + sum_c ctx[c]*w1[m][c]; 4 threads per m
    const int m4 = t >> 2, j = t & 3;
    float hp = 0.f;
    for (int c = j; c < Cn; c += 4) hp += ctx_s[c] * w1[m4 * Cn + c];
    hp += __shfl_xor(hp, 1, 64);
    hp += __shfl_xor(hp, 2, 64);
    if (j == 0) h_s[m4] = hp + b1[m4];
    __syncthreads();

    if (t < 64) {
        float h = h_s[t];
        float mu = h;
        for (int off = 32; off; off >>= 1) mu += __shfl_xor(mu, off, 64);
        mu *= (1.f / 64.f);
        const float d = h - mu;
        float var = d * d;
        for (int off = 32; off; off >>= 1) var += __shfl_xor(var, off, 64);
        var *= (1.f / 64.f);
        h = d * rsqrtf(var + LN_EPS) * ln_g[t] + ln_b[t];
        h_s[t] = fmaxf(h, 0.f);
    }
    __syncthreads();

    float a = b2[t];
    #pragma unroll
    for (int mm = 0; mm < Mn; ++mm) a += h_s[mm] * w2[t * Mn + mm];
    add[b * Cn + t] = a;
}

// K4: out = x + add broadcast. Nontemporal stores keep x resident in L3.
// grid (Ln/4096, Bn*Cn), block 256, each thread 4 float4.
__global__ void k_out(const float* __restrict__ x, const float* __restrict__ add,
                      float* __restrict__ out) {
    const int bc = blockIdx.y;
    const float a = add[bc];
    const size_t base = (size_t)bc * Ln + (size_t)blockIdx.x * 4096;
    const float4* xi = (const float4*)(x + base);
    v4f* xo = (v4f*)(out + base);
    const int t = threadIdx.x;
    #pragma unroll
    for (int k = 0; k < 4; ++k) {
        float4 v = xi[k * 256 + t];
        v4f o = {v.x + a, v.y + a, v.z + a, v.w + a};
        __builtin_nontemporal_store(o, xo + k * 256 + t);
    }
}

extern "C" void kernel_launch(void* const* d_in, const int* in_sizes, int n_in,
                              void* d_out, int out_size, void* d_ws, size_t ws_size,
                              hipStream_t stream) {
    const float* x      = (const float*)d_in[0];
    const float* w_mask = (const float*)d_in[1];
    const float* b_mask = (const float*)d_in[2];
    const float* w1     = (const float*)d_in[3];
    const float* b1     = (const float*)d_in[4];
    const float* ln_g   = (const float*)d_in[5];
    const float* ln_b   = (const float*)d_in[6];
    const float* w2     = (const float*)d_in[7];
    const float* b2     = (const float*)d_in[8];
    float* out = (float*)d_out;

    float* ws   = (float*)d_ws;
    float* ctxU = ws;                                  // Bn*NCH*Cn = 131072 floats
    float* mz   = ctxU + (size_t)Bn * NCH * Cn;        // Bn*NCH*2  = 1024 floats
    float* add  = mz + (size_t)Bn * NCH * 2;           // Bn*Cn     = 4096 floats

    k_pass1<<<dim3(NCH, Bn), 256, 0, stream>>>(x, w_mask, b_mask, ctxU, mz);
    k_mlp<<<Bn, 256, 0, stream>>>(ctxU, mz, w1, b1, ln_g, ln_b, w2, b2, add);
    k_out<<<dim3(Ln / 4096, Bn * Cn), 256, 0, stream>>>(x, add, out);
}